// Round 1
// baseline (989.696 us; speedup 1.0000x reference)
//
#include <hip/hip_runtime.h>
#include <hip/hip_bf16.h>

// GCN: out = relu(gcnconv(relu(gcnconv(x,W1,b1)), W2, b2)) @ Wfc + bfc
// N=50000, E=800000, F0=100, F1=256, F2=128.
// Layer1: aggregate-first (agg over 100-dim x, then GEMM+b1+relu).
// Layer2: transform-first (GEMM 256->128, then aggregate, +b2, relu).

#define F0 100
#define F1 256
#define F2 128

__global__ void deg_init(float* deg, int n) {
    int i = blockIdx.x * blockDim.x + threadIdx.x;
    if (i < n) deg[i] = 1.0f;  // self-loop
}

__global__ void deg_count(const int* __restrict__ dst, float* deg, int e, int n) {
    int i = blockIdx.x * blockDim.x + threadIdx.x;
    if (i < e) {
        int d = dst[i];
        if ((unsigned)d < (unsigned)n) atomicAdd(deg + d, 1.0f);
    }
}

__global__ void deg_rsqrt(float* deg, int n) {
    int i = blockIdx.x * blockDim.x + threadIdx.x;
    if (i < n) deg[i] = rsqrtf(deg[i]);
}

__global__ void edge_coef(const int* __restrict__ src, const int* __restrict__ dst,
                          const float* __restrict__ dinv, float* __restrict__ coef,
                          int e, int n) {
    int i = blockIdx.x * blockDim.x + threadIdx.x;
    if (i < e) {
        int s = src[i], d = dst[i];
        float c = 0.0f;
        if ((unsigned)s < (unsigned)n && (unsigned)d < (unsigned)n)
            c = dinv[s] * dinv[d];
        coef[i] = c;
    }
}

// agg[v][f] = dinv[v]^2 * h[v][f]   (self-loop term; also serves as the init
// since d_ws is poisoned 0xAA before every call)
template <int F>
__global__ void self_init(const float* __restrict__ h, const float* __restrict__ dinv,
                          float* __restrict__ agg, int n) {
    int idx = blockIdx.x * blockDim.x + threadIdx.x;
    if (idx < n * F) {
        int v = idx / F;
        float di = dinv[v];
        agg[idx] = di * di * h[idx];
    }
}

// agg[dst][f] += coef[e] * h[src][f]
template <int F>
__global__ void scatter_edges(const float* __restrict__ h, const int* __restrict__ src,
                              const int* __restrict__ dst, const float* __restrict__ coef,
                              float* __restrict__ agg, int e, int n) {
    int idx = blockIdx.x * blockDim.x + threadIdx.x;
    if (idx >= e * F) return;
    int ed = idx / F;
    int f = idx - ed * F;
    int s = src[ed], d = dst[ed];
    if ((unsigned)s >= (unsigned)n || (unsigned)d >= (unsigned)n) return;
    atomicAdd(agg + d * F + f, coef[ed] * h[s * F + f]);
}

// C[r][c] = relu( sum_k A[r][k] * W[k][c] + bias[c] ), A: [n,100], W: [100,256]
// block = 256 threads (one col each), 8 rows per block. n % 8 == 0 for N=50000.
__global__ __launch_bounds__(256) void gemm_k100_bias_relu(
        const float* __restrict__ A, const float* __restrict__ W,
        const float* __restrict__ bias, float* __restrict__ C, int n) {
    __shared__ float sx[8 * F0];
    int c = threadIdx.x;
    int r0 = blockIdx.x * 8;
    for (int i = threadIdx.x; i < 8 * F0; i += 256) sx[i] = A[r0 * F0 + i];
    __syncthreads();
    float acc[8] = {0, 0, 0, 0, 0, 0, 0, 0};
    for (int k = 0; k < F0; k++) {
        float w = W[k * F1 + c];
#pragma unroll
        for (int r = 0; r < 8; r++) acc[r] += sx[r * F0 + k] * w;
    }
    float b = bias[c];
#pragma unroll
    for (int r = 0; r < 8; r++)
        C[(r0 + r) * F1 + c] = fmaxf(acc[r] + b, 0.0f);
}

// C[r][c] = sum_k A[r][k] * W[k][c], A: [n,256], W: [256,128]. No bias/relu
// (bias applies after aggregation). block = 128 threads, 8 rows per block.
__global__ __launch_bounds__(128) void gemm_k256(
        const float* __restrict__ A, const float* __restrict__ W,
        float* __restrict__ C, int n) {
    __shared__ float sx[8 * F1];
    int c = threadIdx.x;
    int r0 = blockIdx.x * 8;
    for (int i = threadIdx.x; i < 8 * F1; i += 128) sx[i] = A[r0 * F1 + i];
    __syncthreads();
    float acc[8] = {0, 0, 0, 0, 0, 0, 0, 0};
    for (int k = 0; k < F1; k++) {
        float w = W[k * F2 + c];
#pragma unroll
        for (int r = 0; r < 8; r++) acc[r] += sx[r * F1 + k] * w;
    }
#pragma unroll
    for (int r = 0; r < 8; r++)
        C[(r0 + r) * F2 + c] = acc[r];
}

// out[v] = sum_f relu(agg2[v][f] + b2[f]) * Wfc[f] + bfc. One wave per node.
__global__ __launch_bounds__(256) void final_fc(
        const float* __restrict__ agg2, const float* __restrict__ b2,
        const float* __restrict__ Wfc, const float* __restrict__ bfc,
        float* __restrict__ out, int n) {
    int wave = threadIdx.x >> 6;
    int lane = threadIdx.x & 63;
    int v = blockIdx.x * 4 + wave;
    if (v >= n) return;
    const float* row = agg2 + (size_t)v * F2;
    float s = 0.0f;
#pragma unroll
    for (int f0 = 0; f0 < F2; f0 += 64) {
        int f = f0 + lane;
        float val = fmaxf(row[f] + b2[f], 0.0f);
        s += val * Wfc[f];
    }
#pragma unroll
    for (int off = 32; off > 0; off >>= 1) s += __shfl_down(s, off, 64);
    if (lane == 0) out[v] = s + bfc[0];
}

extern "C" void kernel_launch(void* const* d_in, const int* in_sizes, int n_in,
                              void* d_out, int out_size, void* d_ws, size_t ws_size,
                              hipStream_t stream) {
    const float* x   = (const float*)d_in[0];
    const int*   ei  = (const int*)d_in[1];
    const float* W1  = (const float*)d_in[2];
    const float* b1  = (const float*)d_in[3];
    const float* W2  = (const float*)d_in[4];
    const float* b2  = (const float*)d_in[5];
    const float* Wfc = (const float*)d_in[6];
    const float* bfc = (const float*)d_in[7];
    float* out = (float*)d_out;

    const int n = in_sizes[0] / F0;   // 50000
    const int e = in_sizes[1] / 2;    // 800000
    const int* src = ei;
    const int* dst = ei + e;

    // workspace layout (floats)
    float* ws   = (float*)d_ws;
    float* dinv = ws;                         // n
    float* coef = dinv + n;                   // e
    float* aggX = coef + e;                   // n*F0
    float* a1   = aggX + (size_t)n * F0;      // n*F1
    float* h2   = a1   + (size_t)n * F1;      // n*F2
    float* agg2 = h2   + (size_t)n * F2;      // n*F2

    const int B = 256;

    // degrees -> dinv
    deg_init<<<(n + B - 1) / B, B, 0, stream>>>(dinv, n);
    deg_count<<<(e + B - 1) / B, B, 0, stream>>>(dst, dinv, e, n);
    deg_rsqrt<<<(n + B - 1) / B, B, 0, stream>>>(dinv, n);
    edge_coef<<<(e + B - 1) / B, B, 0, stream>>>(src, dst, dinv, coef, e, n);

    // layer 1: aggregate x (100-dim), then GEMM + bias + relu
    self_init<F0><<<((n * F0) + B - 1) / B, B, 0, stream>>>(x, dinv, aggX, n);
    scatter_edges<F0><<<((long long)e * F0 + B - 1) / B, B, 0, stream>>>(
        x, src, dst, coef, aggX, e, n);
    gemm_k100_bias_relu<<<n / 8, 256, 0, stream>>>(aggX, W1, b1, a1, n);

    // layer 2: GEMM 256->128, then aggregate, bias+relu fused into final
    gemm_k256<<<n / 8, 128, 0, stream>>>(a1, W2, h2, n);
    self_init<F2><<<((n * F2) + B - 1) / B, B, 0, stream>>>(h2, dinv, agg2, n);
    scatter_edges<F2><<<((long long)e * F2 + B - 1) / B, B, 0, stream>>>(
        h2, src, dst, coef, agg2, e, n);

    // relu(agg2 + b2) @ Wfc + bfc
    final_fc<<<(n + 3) / 4, 256, 0, stream>>>(agg2, b2, Wfc, bfc, out, n);
}

// Round 2
// 513.718 us; speedup vs baseline: 1.9265x; 1.9265x over previous
//
#include <hip/hip_runtime.h>
#include <hip/hip_bf16.h>

// GCN: out = relu(gcnconv(relu(gcnconv(x,W1,b1)), W2, b2)) @ Wfc + bfc
// N=50000, E=800000, F0=100, F1=256, F2=128.
// Round 2: replace atomic push-scatter with CSR pull-gather (no atomics in
// the hot aggregation). CSR built on-device each call. Layer-2 aggregation
// fused with bias+relu+final FC (agg2 never materialized).

#define F0 100
#define F1 256
#define F2 128

// ---------------- CSR construction ----------------

__global__ void zero_i32(int* p, int n) {
    int i = blockIdx.x * blockDim.x + threadIdx.x;
    if (i < n) p[i] = 0;
}

__global__ void deg_count_i(const int* __restrict__ dst, int* deg, int e) {
    int i = blockIdx.x * blockDim.x + threadIdx.x;
    if (i < e) atomicAdd(deg + dst[i], 1);
}

// dinv[v] = rsqrt(deg[v] + 1)   (+1 = self-loop)
__global__ void make_dinv(const int* __restrict__ deg, float* __restrict__ dinv, int n) {
    int i = blockIdx.x * blockDim.x + threadIdx.x;
    if (i < n) dinv[i] = rsqrtf((float)(deg[i] + 1));
}

// exclusive scan of deg[0..n) -> rowptr[0..n], single workgroup of 1024.
__global__ __launch_bounds__(1024) void scan_rowptr(const int* __restrict__ deg,
                                                    int* __restrict__ rowptr, int n) {
    __shared__ int wsums[16];
    __shared__ int carry;
    int tid = threadIdx.x;
    int lane = tid & 63, wid = tid >> 6;
    if (tid == 0) carry = 0;
    __syncthreads();
    for (int base = 0; base < n; base += 1024) {
        int i = base + tid;
        int v = (i < n) ? deg[i] : 0;
        int s = v;
#pragma unroll
        for (int off = 1; off < 64; off <<= 1) {
            int t = __shfl_up(s, off, 64);
            if (lane >= off) s += t;
        }
        if (lane == 63) wsums[wid] = s;
        __syncthreads();
        if (wid == 0) {
            int ws = (lane < 16) ? wsums[lane] : 0;
#pragma unroll
            for (int off = 1; off < 16; off <<= 1) {
                int t = __shfl_up(ws, off, 64);
                if (lane >= off) ws += t;
            }
            if (lane < 16) wsums[lane] = ws;  // inclusive over waves
        }
        __syncthreads();
        int prev = (wid == 0) ? 0 : wsums[wid - 1];
        int excl = carry + prev + (s - v);
        if (i < n) rowptr[i] = excl;
        int total = wsums[15];
        __syncthreads();
        if (tid == 0) carry += total;
        __syncthreads();
    }
    if (tid == 0) rowptr[n] = carry;
}

__global__ void csr_fill(const int* __restrict__ src, const int* __restrict__ dst,
                         int* cursor, int* __restrict__ csr, int e) {
    int i = blockIdx.x * blockDim.x + threadIdx.x;
    if (i < e) {
        int pos = atomicAdd(cursor + dst[i], 1);
        csr[pos] = src[i];
    }
}

// ---------------- pull-gather aggregation ----------------

// agg[v][:] = dinv[v] * ( sum_{s in in(v)} dinv[s]*x[s][:]  +  dinv[v]*x[v][:] )
// One wave per node; lanes 0..49 each hold a float2 (100 floats/row).
__global__ __launch_bounds__(256) void pull_f100(
        const float* __restrict__ x, const int* __restrict__ rowptr,
        const int* __restrict__ csr, const float* __restrict__ dinv,
        float* __restrict__ agg, int n) {
    int wave = threadIdx.x >> 6, lane = threadIdx.x & 63;
    int v = blockIdx.x * 4 + wave;
    if (v >= n) return;
    int beg = rowptr[v], end = rowptr[v + 1];
    float dv = dinv[v];
    bool act = lane < 50;
    float2 acc = {0.f, 0.f};
    if (act) {
        float2 hv = ((const float2*)(x + (size_t)v * F0))[lane];
        acc.x = dv * hv.x;
        acc.y = dv * hv.y;
    }
    int j = beg;
    for (; j + 1 < end; j += 2) {
        int s0 = csr[j], s1 = csr[j + 1];
        float c0 = dinv[s0], c1 = dinv[s1];
        if (act) {
            float2 h0 = ((const float2*)(x + (size_t)s0 * F0))[lane];
            float2 h1 = ((const float2*)(x + (size_t)s1 * F0))[lane];
            acc.x += c0 * h0.x + c1 * h1.x;
            acc.y += c0 * h0.y + c1 * h1.y;
        }
    }
    if (j < end) {
        int s = csr[j];
        float c = dinv[s];
        if (act) {
            float2 h = ((const float2*)(x + (size_t)s * F0))[lane];
            acc.x += c * h.x;
            acc.y += c * h.y;
        }
    }
    if (act) {
        float2 r;
        r.x = dv * acc.x;
        r.y = dv * acc.y;
        ((float2*)(agg + (size_t)v * F0))[lane] = r;
    }
}

// Fused layer-2 aggregation + bias + relu + final FC:
// out[v] = sum_f relu( dinv[v]*(sum dinv[s]*h2[s][f] + dinv[v]*h2[v][f]) + b2[f] ) * Wfc[f] + bfc
// One wave per node; each lane holds a float2 (128 floats/row).
__global__ __launch_bounds__(256) void pull_f128_fused(
        const float* __restrict__ h2, const int* __restrict__ rowptr,
        const int* __restrict__ csr, const float* __restrict__ dinv,
        const float* __restrict__ b2, const float* __restrict__ Wfc,
        const float* __restrict__ bfc, float* __restrict__ out, int n) {
    int wave = threadIdx.x >> 6, lane = threadIdx.x & 63;
    int v = blockIdx.x * 4 + wave;
    if (v >= n) return;
    int beg = rowptr[v], end = rowptr[v + 1];
    float dv = dinv[v];
    float2 hv = ((const float2*)(h2 + (size_t)v * F2))[lane];
    float2 acc;
    acc.x = dv * hv.x;
    acc.y = dv * hv.y;
    int j = beg;
    for (; j + 1 < end; j += 2) {
        int s0 = csr[j], s1 = csr[j + 1];
        float c0 = dinv[s0], c1 = dinv[s1];
        float2 h0 = ((const float2*)(h2 + (size_t)s0 * F2))[lane];
        float2 h1 = ((const float2*)(h2 + (size_t)s1 * F2))[lane];
        acc.x += c0 * h0.x + c1 * h1.x;
        acc.y += c0 * h0.y + c1 * h1.y;
    }
    if (j < end) {
        int s = csr[j];
        float c = dinv[s];
        float2 h = ((const float2*)(h2 + (size_t)s * F2))[lane];
        acc.x += c * h.x;
        acc.y += c * h.y;
    }
    int f = lane * 2;
    float a0 = fmaxf(dv * acc.x + b2[f], 0.f) * Wfc[f];
    float a1 = fmaxf(dv * acc.y + b2[f + 1], 0.f) * Wfc[f + 1];
    float s = a0 + a1;
#pragma unroll
    for (int off = 32; off > 0; off >>= 1) s += __shfl_down(s, off, 64);
    if (lane == 0) out[v] = s + bfc[0];
}

// ---------------- dense transforms (fp32) ----------------

// C[r][c] = relu( sum_k A[r][k]*W[k][c] + bias[c] ), A:[n,100], W:[100,256]
__global__ __launch_bounds__(256) void gemm_k100_bias_relu(
        const float* __restrict__ A, const float* __restrict__ W,
        const float* __restrict__ bias, float* __restrict__ C, int n) {
    __shared__ float sx[8 * F0];
    int c = threadIdx.x;
    int r0 = blockIdx.x * 8;
    for (int i = threadIdx.x; i < 8 * F0; i += 256) sx[i] = A[r0 * F0 + i];
    __syncthreads();
    float acc[8] = {0, 0, 0, 0, 0, 0, 0, 0};
    for (int k = 0; k < F0; k++) {
        float w = W[k * F1 + c];
#pragma unroll
        for (int r = 0; r < 8; r++) acc[r] += sx[r * F0 + k] * w;
    }
    float b = bias[c];
#pragma unroll
    for (int r = 0; r < 8; r++)
        C[(r0 + r) * F1 + c] = fmaxf(acc[r] + b, 0.0f);
}

// C[r][c] = sum_k A[r][k]*W[k][c], A:[n,256], W:[256,128] (bias after agg)
__global__ __launch_bounds__(128) void gemm_k256(
        const float* __restrict__ A, const float* __restrict__ W,
        float* __restrict__ C, int n) {
    __shared__ float sx[8 * F1];
    int c = threadIdx.x;
    int r0 = blockIdx.x * 8;
    for (int i = threadIdx.x; i < 8 * F1; i += 128) sx[i] = A[r0 * F1 + i];
    __syncthreads();
    float acc[8] = {0, 0, 0, 0, 0, 0, 0, 0};
    for (int k = 0; k < F1; k++) {
        float w = W[k * F2 + c];
#pragma unroll
        for (int r = 0; r < 8; r++) acc[r] += sx[r * F1 + k] * w;
    }
#pragma unroll
    for (int r = 0; r < 8; r++)
        C[(r0 + r) * F2 + c] = acc[r];
}

// ---------------- launch ----------------

static inline size_t align16(size_t x) { return (x + 3) & ~(size_t)3; }  // in 4B elems

extern "C" void kernel_launch(void* const* d_in, const int* in_sizes, int n_in,
                              void* d_out, int out_size, void* d_ws, size_t ws_size,
                              hipStream_t stream) {
    const float* x   = (const float*)d_in[0];
    const int*   ei  = (const int*)d_in[1];
    const float* W1  = (const float*)d_in[2];
    const float* b1  = (const float*)d_in[3];
    const float* W2  = (const float*)d_in[4];
    const float* b2  = (const float*)d_in[5];
    const float* Wfc = (const float*)d_in[6];
    const float* bfc = (const float*)d_in[7];
    float* out = (float*)d_out;

    const int n = in_sizes[0] / F0;   // 50000
    const int e = in_sizes[1] / 2;    // 800000
    const int* src = ei;
    const int* dst = ei + e;

    // workspace layout (4-byte elements, each region 16B-aligned)
    char* wsb = (char*)d_ws;
    size_t off = 0;
    int* deg    = (int*)(wsb + 4 * off); off = align16(off + n);
    int* rowptr = (int*)(wsb + 4 * off); off = align16(off + n + 1);
    int* cursor = (int*)(wsb + 4 * off); off = align16(off + n);
    int* csr    = (int*)(wsb + 4 * off); off = align16(off + e);
    float* dinv = (float*)(wsb + 4 * off); off = align16(off + n);
    float* aggX = (float*)(wsb + 4 * off); off = align16(off + (size_t)n * F0);
    float* a1   = (float*)(wsb + 4 * off); off = align16(off + (size_t)n * F1);
    float* h2   = (float*)(wsb + 4 * off); off = align16(off + (size_t)n * F2);

    const int B = 256;

    // CSR build
    zero_i32<<<(n + B - 1) / B, B, 0, stream>>>(deg, n);
    deg_count_i<<<(e + B - 1) / B, B, 0, stream>>>(dst, deg, e);
    make_dinv<<<(n + B - 1) / B, B, 0, stream>>>(deg, dinv, n);
    scan_rowptr<<<1, 1024, 0, stream>>>(deg, rowptr, n);
    hipMemcpyAsync(cursor, rowptr, (size_t)n * 4, hipMemcpyDeviceToDevice, stream);
    csr_fill<<<(e + B - 1) / B, B, 0, stream>>>(src, dst, cursor, csr, e);

    // layer 1: pull-aggregate x (100-dim), then GEMM + bias + relu
    pull_f100<<<(n + 3) / 4, 256, 0, stream>>>(x, rowptr, csr, dinv, aggX, n);
    gemm_k100_bias_relu<<<n / 8, 256, 0, stream>>>(aggX, W1, b1, a1, n);

    // layer 2: GEMM 256->128, then fused pull-aggregate + bias + relu + FC
    gemm_k256<<<n / 8, 128, 0, stream>>>(a1, W2, h2, n);
    pull_f128_fused<<<(n + 3) / 4, 256, 0, stream>>>(h2, rowptr, csr, dinv,
                                                     b2, Wfc, bfc, out, n);
}

// Round 3
// 479.626 us; speedup vs baseline: 2.0635x; 1.0711x over previous
//
#include <hip/hip_runtime.h>
#include <hip/hip_bf16.h>

// GCN: out = relu(gcnconv(relu(gcnconv(x,W1,b1)), W2, b2)) @ Wfc + bfc
// N=50000, E=800000, F0=100, F1=256, F2=128.
// Round 3: register-tiled fp32 GEMMs (64x64 tile, 4x4 per thread, k-major
// LDS layout so the inner loop is 2x ds_read_b128 per 16 FMAs). CSR pull
// aggregation unchanged from round 2.

#define F0 100
#define F1 256
#define F2 128
#define KPAD 68  // 64 + 4 pad, multiple of 4 so float4 LDS reads stay 16B-aligned

// ---------------- CSR construction ----------------

__global__ void zero_i32(int* p, int n) {
    int i = blockIdx.x * blockDim.x + threadIdx.x;
    if (i < n) p[i] = 0;
}

__global__ void deg_count_i(const int* __restrict__ dst, int* deg, int e) {
    int i = blockIdx.x * blockDim.x + threadIdx.x;
    if (i < e) atomicAdd(deg + dst[i], 1);
}

__global__ void make_dinv(const int* __restrict__ deg, float* __restrict__ dinv, int n) {
    int i = blockIdx.x * blockDim.x + threadIdx.x;
    if (i < n) dinv[i] = rsqrtf((float)(deg[i] + 1));
}

// exclusive scan of deg[0..n) -> rowptr[0..n], single workgroup of 1024.
__global__ __launch_bounds__(1024) void scan_rowptr(const int* __restrict__ deg,
                                                    int* __restrict__ rowptr, int n) {
    __shared__ int wsums[16];
    __shared__ int carry;
    int tid = threadIdx.x;
    int lane = tid & 63, wid = tid >> 6;
    if (tid == 0) carry = 0;
    __syncthreads();
    for (int base = 0; base < n; base += 1024) {
        int i = base + tid;
        int v = (i < n) ? deg[i] : 0;
        int s = v;
#pragma unroll
        for (int off = 1; off < 64; off <<= 1) {
            int t = __shfl_up(s, off, 64);
            if (lane >= off) s += t;
        }
        if (lane == 63) wsums[wid] = s;
        __syncthreads();
        if (wid == 0) {
            int ws = (lane < 16) ? wsums[lane] : 0;
#pragma unroll
            for (int off = 1; off < 16; off <<= 1) {
                int t = __shfl_up(ws, off, 64);
                if (lane >= off) ws += t;
            }
            if (lane < 16) wsums[lane] = ws;  // inclusive over waves
        }
        __syncthreads();
        int prev = (wid == 0) ? 0 : wsums[wid - 1];
        int excl = carry + prev + (s - v);
        if (i < n) rowptr[i] = excl;
        int total = wsums[15];
        __syncthreads();
        if (tid == 0) carry += total;
        __syncthreads();
    }
    if (tid == 0) rowptr[n] = carry;
}

__global__ void csr_fill(const int* __restrict__ src, const int* __restrict__ dst,
                         int* cursor, int* __restrict__ csr, int e) {
    int i = blockIdx.x * blockDim.x + threadIdx.x;
    if (i < e) {
        int pos = atomicAdd(cursor + dst[i], 1);
        csr[pos] = src[i];
    }
}

// ---------------- pull-gather aggregation ----------------

__global__ __launch_bounds__(256) void pull_f100(
        const float* __restrict__ x, const int* __restrict__ rowptr,
        const int* __restrict__ csr, const float* __restrict__ dinv,
        float* __restrict__ agg, int n) {
    int wave = threadIdx.x >> 6, lane = threadIdx.x & 63;
    int v = blockIdx.x * 4 + wave;
    if (v >= n) return;
    int beg = rowptr[v], end = rowptr[v + 1];
    float dv = dinv[v];
    bool act = lane < 50;
    float2 acc = {0.f, 0.f};
    if (act) {
        float2 hv = ((const float2*)(x + (size_t)v * F0))[lane];
        acc.x = dv * hv.x;
        acc.y = dv * hv.y;
    }
    int j = beg;
    for (; j + 1 < end; j += 2) {
        int s0 = csr[j], s1 = csr[j + 1];
        float c0 = dinv[s0], c1 = dinv[s1];
        if (act) {
            float2 h0 = ((const float2*)(x + (size_t)s0 * F0))[lane];
            float2 h1 = ((const float2*)(x + (size_t)s1 * F0))[lane];
            acc.x += c0 * h0.x + c1 * h1.x;
            acc.y += c0 * h0.y + c1 * h1.y;
        }
    }
    if (j < end) {
        int s = csr[j];
        float c = dinv[s];
        if (act) {
            float2 h = ((const float2*)(x + (size_t)s * F0))[lane];
            acc.x += c * h.x;
            acc.y += c * h.y;
        }
    }
    if (act) {
        float2 r;
        r.x = dv * acc.x;
        r.y = dv * acc.y;
        ((float2*)(agg + (size_t)v * F0))[lane] = r;
    }
}

// Fused layer-2 aggregation + bias + relu + final FC.
__global__ __launch_bounds__(256) void pull_f128_fused(
        const float* __restrict__ h2, const int* __restrict__ rowptr,
        const int* __restrict__ csr, const float* __restrict__ dinv,
        const float* __restrict__ b2, const float* __restrict__ Wfc,
        const float* __restrict__ bfc, float* __restrict__ out, int n) {
    int wave = threadIdx.x >> 6, lane = threadIdx.x & 63;
    int v = blockIdx.x * 4 + wave;
    if (v >= n) return;
    int beg = rowptr[v], end = rowptr[v + 1];
    float dv = dinv[v];
    float2 hv = ((const float2*)(h2 + (size_t)v * F2))[lane];
    float2 acc;
    acc.x = dv * hv.x;
    acc.y = dv * hv.y;
    int j = beg;
    for (; j + 1 < end; j += 2) {
        int s0 = csr[j], s1 = csr[j + 1];
        float c0 = dinv[s0], c1 = dinv[s1];
        float2 h0 = ((const float2*)(h2 + (size_t)s0 * F2))[lane];
        float2 h1 = ((const float2*)(h2 + (size_t)s1 * F2))[lane];
        acc.x += c0 * h0.x + c1 * h1.x;
        acc.y += c0 * h0.y + c1 * h1.y;
    }
    if (j < end) {
        int s = csr[j];
        float c = dinv[s];
        float2 h = ((const float2*)(h2 + (size_t)s * F2))[lane];
        acc.x += c * h.x;
        acc.y += c * h.y;
    }
    int f = lane * 2;
    float a0 = fmaxf(dv * acc.x + b2[f], 0.f) * Wfc[f];
    float a1 = fmaxf(dv * acc.y + b2[f + 1], 0.f) * Wfc[f + 1];
    float s = a0 + a1;
#pragma unroll
    for (int off = 32; off > 0; off >>= 1) s += __shfl_down(s, off, 64);
    if (lane == 0) out[v] = s + bfc[0];
}

// ---------------- dense transforms (fp32, register-tiled) ----------------

// C = relu(A @ W + bias), A:[n,100], W:[100,256]. 64x64 tile, 4x4/thread.
// LDS k-major: As[k][row(68)], Bs[k][col(68)] -> inner loop 2x ds_read_b128.
__global__ __launch_bounds__(256) void gemm1_tiled(
        const float* __restrict__ A, const float* __restrict__ W,
        const float* __restrict__ bias, float* __restrict__ C, int n) {
    __shared__ float As[F0 * KPAD];
    __shared__ float Bs[F0 * KPAD];
    int tid = threadIdx.x;
    int r0 = blockIdx.x * 64;
    int c0 = blockIdx.y * 64;

    // stage A (transposed): 64 rows x 25 float4
    for (int idx = tid; idx < 64 * 25; idx += 256) {
        int row = idx / 25, kq = idx - row * 25;
        int gr = r0 + row;
        if (gr >= n) gr = n - 1;
        float4 v = ((const float4*)(A + (size_t)gr * F0))[kq];
        int k = 4 * kq;
        As[(k + 0) * KPAD + row] = v.x;
        As[(k + 1) * KPAD + row] = v.y;
        As[(k + 2) * KPAD + row] = v.z;
        As[(k + 3) * KPAD + row] = v.w;
    }
    // stage B: 100 k x 16 float4
    for (int idx = tid; idx < F0 * 16; idx += 256) {
        int k = idx >> 4, cq = idx & 15;
        ((float4*)(Bs + k * KPAD))[cq] = ((const float4*)(W + k * F1 + c0))[cq];
    }
    __syncthreads();

    int tc = tid & 15, tr = tid >> 4;
    float acc[4][4] = {};
    for (int k = 0; k < F0; k++) {
        float4 a = *(const float4*)(As + k * KPAD + 4 * tr);
        float4 b = *(const float4*)(Bs + k * KPAD + 4 * tc);
        float av[4] = {a.x, a.y, a.z, a.w};
        float bv[4] = {b.x, b.y, b.z, b.w};
#pragma unroll
        for (int i = 0; i < 4; i++)
#pragma unroll
            for (int j = 0; j < 4; j++) acc[i][j] += av[i] * bv[j];
    }
    float4 bb = *(const float4*)(bias + c0 + 4 * tc);
    float bvv[4] = {bb.x, bb.y, bb.z, bb.w};
#pragma unroll
    for (int i = 0; i < 4; i++) {
        int gr = r0 + 4 * tr + i;
        if (gr < n) {
            float4 o;
            o.x = fmaxf(acc[i][0] + bvv[0], 0.f);
            o.y = fmaxf(acc[i][1] + bvv[1], 0.f);
            o.z = fmaxf(acc[i][2] + bvv[2], 0.f);
            o.w = fmaxf(acc[i][3] + bvv[3], 0.f);
            ((float4*)(C + (size_t)gr * F1 + c0))[tc] = o;
        }
    }
}

// C = A @ W, A:[n,256], W:[256,128]. 64x64 tile, 4x4/thread, K chunked by 64.
__global__ __launch_bounds__(256) void gemm2_tiled(
        const float* __restrict__ A, const float* __restrict__ W,
        float* __restrict__ C, int n) {
    __shared__ float As[64 * KPAD];
    __shared__ float Bs[64 * KPAD];
    int tid = threadIdx.x;
    int r0 = blockIdx.x * 64;
    int c0 = blockIdx.y * 64;
    int tc = tid & 15, tr = tid >> 4;
    float acc[4][4] = {};

    for (int k0 = 0; k0 < F1; k0 += 64) {
        if (k0) __syncthreads();
        // stage A (transposed): 64 rows x 16 float4
        for (int idx = tid; idx < 64 * 16; idx += 256) {
            int row = idx >> 4, kq = idx & 15;
            int gr = r0 + row;
            if (gr >= n) gr = n - 1;
            float4 v = ((const float4*)(A + (size_t)gr * F1 + k0))[kq];
            int k = 4 * kq;
            As[(k + 0) * KPAD + row] = v.x;
            As[(k + 1) * KPAD + row] = v.y;
            As[(k + 2) * KPAD + row] = v.z;
            As[(k + 3) * KPAD + row] = v.w;
        }
        // stage B: 64 k x 16 float4
        for (int idx = tid; idx < 64 * 16; idx += 256) {
            int k = idx >> 4, cq = idx & 15;
            ((float4*)(Bs + k * KPAD))[cq] =
                ((const float4*)(W + (k0 + k) * F2 + c0))[cq];
        }
        __syncthreads();
#pragma unroll 4
        for (int k = 0; k < 64; k++) {
            float4 a = *(const float4*)(As + k * KPAD + 4 * tr);
            float4 b = *(const float4*)(Bs + k * KPAD + 4 * tc);
            float av[4] = {a.x, a.y, a.z, a.w};
            float bv[4] = {b.x, b.y, b.z, b.w};
#pragma unroll
            for (int i = 0; i < 4; i++)
#pragma unroll
                for (int j = 0; j < 4; j++) acc[i][j] += av[i] * bv[j];
        }
    }
#pragma unroll
    for (int i = 0; i < 4; i++) {
        int gr = r0 + 4 * tr + i;
        if (gr < n) {
            float4 o = {acc[i][0], acc[i][1], acc[i][2], acc[i][3]};
            ((float4*)(C + (size_t)gr * F2 + c0))[tc] = o;
        }
    }
}

// ---------------- launch ----------------

static inline size_t align16(size_t x) { return (x + 3) & ~(size_t)3; }  // in 4B elems

extern "C" void kernel_launch(void* const* d_in, const int* in_sizes, int n_in,
                              void* d_out, int out_size, void* d_ws, size_t ws_size,
                              hipStream_t stream) {
    const float* x   = (const float*)d_in[0];
    const int*   ei  = (const int*)d_in[1];
    const float* W1  = (const float*)d_in[2];
    const float* b1  = (const float*)d_in[3];
    const float* W2  = (const float*)d_in[4];
    const float* b2  = (const float*)d_in[5];
    const float* Wfc = (const float*)d_in[6];
    const float* bfc = (const float*)d_in[7];
    float* out = (float*)d_out;

    const int n = in_sizes[0] / F0;   // 50000
    const int e = in_sizes[1] / 2;    // 800000
    const int* src = ei;
    const int* dst = ei + e;

    // workspace layout (4-byte elements, each region 16B-aligned)
    char* wsb = (char*)d_ws;
    size_t off = 0;
    int* deg    = (int*)(wsb + 4 * off); off = align16(off + n);
    int* rowptr = (int*)(wsb + 4 * off); off = align16(off + n + 1);
    int* cursor = (int*)(wsb + 4 * off); off = align16(off + n);
    int* csr    = (int*)(wsb + 4 * off); off = align16(off + e);
    float* dinv = (float*)(wsb + 4 * off); off = align16(off + n);
    float* aggX = (float*)(wsb + 4 * off); off = align16(off + (size_t)n * F0);
    float* a1   = (float*)(wsb + 4 * off); off = align16(off + (size_t)n * F1);
    float* h2   = (float*)(wsb + 4 * off); off = align16(off + (size_t)n * F2);

    const int B = 256;
    const int rblocks = (n + 63) / 64;

    // CSR build
    zero_i32<<<(n + B - 1) / B, B, 0, stream>>>(deg, n);
    deg_count_i<<<(e + B - 1) / B, B, 0, stream>>>(dst, deg, e);
    make_dinv<<<(n + B - 1) / B, B, 0, stream>>>(deg, dinv, n);
    scan_rowptr<<<1, 1024, 0, stream>>>(deg, rowptr, n);
    hipMemcpyAsync(cursor, rowptr, (size_t)n * 4, hipMemcpyDeviceToDevice, stream);
    csr_fill<<<(e + B - 1) / B, B, 0, stream>>>(src, dst, cursor, csr, e);

    // layer 1: pull-aggregate x (100-dim), then tiled GEMM + bias + relu
    pull_f100<<<(n + 3) / 4, 256, 0, stream>>>(x, rowptr, csr, dinv, aggX, n);
    gemm1_tiled<<<dim3(rblocks, F1 / 64), 256, 0, stream>>>(aggX, W1, b1, a1, n);

    // layer 2: tiled GEMM 256->128, then fused pull + bias + relu + FC
    gemm2_tiled<<<dim3(rblocks, F2 / 64), 256, 0, stream>>>(a1, W2, h2, n);
    pull_f128_fused<<<(n + 3) / 4, 256, 0, stream>>>(h2, rowptr, csr, dinv,
                                                     b2, Wfc, bfc, out, n);
}

// Round 5
// 444.827 us; speedup vs baseline: 2.2249x; 1.0782x over previous
//
#include <hip/hip_runtime.h>
#include <hip/hip_bf16.h>

// GCN: out = relu(gcnconv(relu(gcnconv(x,W1,b1)), W2, b2)) @ Wfc + bfc
// N=50000, E=800000, F0=100, F1=256, F2=128.
// Round 5: all-fp32 (bf16 anywhere in the value path blows the harness's
// ~6e-6 relative threshold — round-4 post-mortem). Pull kernels rebuilt for
// memory-level parallelism: lane-parallel index/coef prefetch (one coalesced
// load per 64 edges), two rows per load instruction (half-wave per edge),
// 4-pair unroll. fp32 register-tiled GEMMs unchanged from round 3.

#define F0 100
#define F1 256
#define F2 128
#define KPAD 68  // 64 + 4 pad for LDS float4 tiles

// ---------------- CSR construction ----------------

__global__ void zero_i32(int* p, int n) {
    int i = blockIdx.x * blockDim.x + threadIdx.x;
    if (i < n) p[i] = 0;
}

__global__ void deg_count_i(const int* __restrict__ dst, int* deg, int e) {
    int i = blockIdx.x * blockDim.x + threadIdx.x;
    if (i < e) atomicAdd(deg + dst[i], 1);
}

__global__ void make_dinv(const int* __restrict__ deg, float* __restrict__ dinv, int n) {
    int i = blockIdx.x * blockDim.x + threadIdx.x;
    if (i < n) dinv[i] = rsqrtf((float)(deg[i] + 1));
}

// exclusive scan of deg[0..n) -> rowptr[0..n], single workgroup of 1024.
__global__ __launch_bounds__(1024) void scan_rowptr(const int* __restrict__ deg,
                                                    int* __restrict__ rowptr, int n) {
    __shared__ int wsums[16];
    __shared__ int carry;
    int tid = threadIdx.x;
    int lane = tid & 63, wid = tid >> 6;
    if (tid == 0) carry = 0;
    __syncthreads();
    for (int base = 0; base < n; base += 1024) {
        int i = base + tid;
        int v = (i < n) ? deg[i] : 0;
        int s = v;
#pragma unroll
        for (int off = 1; off < 64; off <<= 1) {
            int t = __shfl_up(s, off, 64);
            if (lane >= off) s += t;
        }
        if (lane == 63) wsums[wid] = s;
        __syncthreads();
        if (wid == 0) {
            int ws = (lane < 16) ? wsums[lane] : 0;
#pragma unroll
            for (int off = 1; off < 16; off <<= 1) {
                int t = __shfl_up(ws, off, 64);
                if (lane >= off) ws += t;
            }
            if (lane < 16) wsums[lane] = ws;  // inclusive over waves
        }
        __syncthreads();
        int prev = (wid == 0) ? 0 : wsums[wid - 1];
        int excl = carry + prev + (s - v);
        if (i < n) rowptr[i] = excl;
        int total = wsums[15];
        __syncthreads();
        if (tid == 0) carry += total;
        __syncthreads();
    }
    if (tid == 0) rowptr[n] = carry;
}

__global__ void csr_fill(const int* __restrict__ src, const int* __restrict__ dst,
                         int* cursor, int* __restrict__ csr, int e) {
    int i = blockIdx.x * blockDim.x + threadIdx.x;
    if (i < e) {
        int pos = atomicAdd(cursor + dst[i], 1);
        csr[pos] = src[i];
    }
}

// ---------------- pull-gather aggregation (fp32, high-MLP) ----------------

// aggX[v][:] = dinv[v]*( sum_{s in in(v)} dinv[s]*x[s][:] + dinv[v]*x[v][:] )
// One wave/node. Row = 400B = 25 float4. Lanes 0-24 process even edges,
// lanes 32-56 odd edges (two rows per load instruction); fold at the end.
__global__ __launch_bounds__(256) void pull_f100(
        const float* __restrict__ x, const int* __restrict__ rowptr,
        const int* __restrict__ csr, const float* __restrict__ dinv,
        float* __restrict__ agg, int n) {
    int wave = threadIdx.x >> 6, lane = threadIdx.x & 63;
    int v = blockIdx.x * 4 + wave;
    if (v >= n) return;
    int beg = rowptr[v], end = rowptr[v + 1];
    float dv = dinv[v];
    int half = lane >> 5;    // which edge of the pair
    int q = lane & 31;       // float4 slot within row
    bool act = q < 25;
    float4 acc = {0.f, 0.f, 0.f, 0.f};

    for (int base = beg; base < end; base += 64) {
        int cnt = min(64, end - base);
        int sidx = (lane < cnt) ? csr[base + lane] : v;
        float scoef = (lane < cnt) ? dinv[sidx] : 0.f;
        int npairs = (cnt + 1) >> 1;
        int p = 0;
        for (; p + 4 <= npairs; p += 4) {
            int s0 = __shfl(sidx, 2 * p + half, 64);
            int s1 = __shfl(sidx, 2 * (p + 1) + half, 64);
            int s2 = __shfl(sidx, 2 * (p + 2) + half, 64);
            int s3 = __shfl(sidx, 2 * (p + 3) + half, 64);
            float c0 = __shfl(scoef, 2 * p + half, 64);
            float c1 = __shfl(scoef, 2 * (p + 1) + half, 64);
            float c2 = __shfl(scoef, 2 * (p + 2) + half, 64);
            float c3 = __shfl(scoef, 2 * (p + 3) + half, 64);
            if (act) {
                float4 r0 = ((const float4*)(x + (size_t)s0 * F0))[q];
                float4 r1 = ((const float4*)(x + (size_t)s1 * F0))[q];
                float4 r2 = ((const float4*)(x + (size_t)s2 * F0))[q];
                float4 r3 = ((const float4*)(x + (size_t)s3 * F0))[q];
                acc.x += c0 * r0.x + c1 * r1.x + c2 * r2.x + c3 * r3.x;
                acc.y += c0 * r0.y + c1 * r1.y + c2 * r2.y + c3 * r3.y;
                acc.z += c0 * r0.z + c1 * r1.z + c2 * r2.z + c3 * r3.z;
                acc.w += c0 * r0.w + c1 * r1.w + c2 * r2.w + c3 * r3.w;
            }
        }
        for (; p < npairs; p++) {
            int s0 = __shfl(sidx, 2 * p + half, 64);
            float c0 = __shfl(scoef, 2 * p + half, 64);
            if (act) {
                float4 r0 = ((const float4*)(x + (size_t)s0 * F0))[q];
                acc.x += c0 * r0.x;
                acc.y += c0 * r0.y;
                acc.z += c0 * r0.z;
                acc.w += c0 * r0.w;
            }
        }
    }
    // fold odd-edge half into even half (all lanes execute the shfls)
    float ox = __shfl_down(acc.x, 32, 64);
    float oy = __shfl_down(acc.y, 32, 64);
    float oz = __shfl_down(acc.z, 32, 64);
    float ow = __shfl_down(acc.w, 32, 64);
    if (half == 0 && act) {
        float4 hv = ((const float4*)(x + (size_t)v * F0))[q];
        float4 r;
        r.x = dv * (acc.x + ox + dv * hv.x);
        r.y = dv * (acc.y + oy + dv * hv.y);
        r.z = dv * (acc.z + oz + dv * hv.z);
        r.w = dv * (acc.w + ow + dv * hv.w);
        ((float4*)(agg + (size_t)v * F0))[q] = r;
    }
}

// Fused layer-2 aggregation + bias + relu + final FC.
// Row = 512B = 32 float4. Lanes 0-31 even edges, 32-63 odd edges.
__global__ __launch_bounds__(256) void pull_f128_fused(
        const float* __restrict__ h2, const int* __restrict__ rowptr,
        const int* __restrict__ csr, const float* __restrict__ dinv,
        const float* __restrict__ b2, const float* __restrict__ Wfc,
        const float* __restrict__ bfc, float* __restrict__ out, int n) {
    int wave = threadIdx.x >> 6, lane = threadIdx.x & 63;
    int v = blockIdx.x * 4 + wave;
    if (v >= n) return;
    int beg = rowptr[v], end = rowptr[v + 1];
    float dv = dinv[v];
    int half = lane >> 5;
    int q = lane & 31;
    float4 acc = {0.f, 0.f, 0.f, 0.f};

    for (int base = beg; base < end; base += 64) {
        int cnt = min(64, end - base);
        int sidx = (lane < cnt) ? csr[base + lane] : v;
        float scoef = (lane < cnt) ? dinv[sidx] : 0.f;
        int npairs = (cnt + 1) >> 1;
        int p = 0;
        for (; p + 4 <= npairs; p += 4) {
            int s0 = __shfl(sidx, 2 * p + half, 64);
            int s1 = __shfl(sidx, 2 * (p + 1) + half, 64);
            int s2 = __shfl(sidx, 2 * (p + 2) + half, 64);
            int s3 = __shfl(sidx, 2 * (p + 3) + half, 64);
            float c0 = __shfl(scoef, 2 * p + half, 64);
            float c1 = __shfl(scoef, 2 * (p + 1) + half, 64);
            float c2 = __shfl(scoef, 2 * (p + 2) + half, 64);
            float c3 = __shfl(scoef, 2 * (p + 3) + half, 64);
            float4 r0 = ((const float4*)(h2 + (size_t)s0 * F2))[q];
            float4 r1 = ((const float4*)(h2 + (size_t)s1 * F2))[q];
            float4 r2 = ((const float4*)(h2 + (size_t)s2 * F2))[q];
            float4 r3 = ((const float4*)(h2 + (size_t)s3 * F2))[q];
            acc.x += c0 * r0.x + c1 * r1.x + c2 * r2.x + c3 * r3.x;
            acc.y += c0 * r0.y + c1 * r1.y + c2 * r2.y + c3 * r3.y;
            acc.z += c0 * r0.z + c1 * r1.z + c2 * r2.z + c3 * r3.z;
            acc.w += c0 * r0.w + c1 * r1.w + c2 * r2.w + c3 * r3.w;
        }
        for (; p < npairs; p++) {
            int s0 = __shfl(sidx, 2 * p + half, 64);
            float c0 = __shfl(scoef, 2 * p + half, 64);
            float4 r0 = ((const float4*)(h2 + (size_t)s0 * F2))[q];
            acc.x += c0 * r0.x;
            acc.y += c0 * r0.y;
            acc.z += c0 * r0.z;
            acc.w += c0 * r0.w;
        }
    }
    // fold odd half into even half
    float ox = __shfl_down(acc.x, 32, 64);
    float oy = __shfl_down(acc.y, 32, 64);
    float oz = __shfl_down(acc.z, 32, 64);
    float ow = __shfl_down(acc.w, 32, 64);
    float part = 0.f;
    if (half == 0) {
        float4 hv = ((const float4*)(h2 + (size_t)v * F2))[q];
        float4 b2v = ((const float4*)b2)[q];
        float4 wv = ((const float4*)Wfc)[q];
        float t0 = dv * (acc.x + ox + dv * hv.x);
        float t1 = dv * (acc.y + oy + dv * hv.y);
        float t2 = dv * (acc.z + oz + dv * hv.z);
        float t3 = dv * (acc.w + ow + dv * hv.w);
        part = fmaxf(t0 + b2v.x, 0.f) * wv.x + fmaxf(t1 + b2v.y, 0.f) * wv.y +
               fmaxf(t2 + b2v.z, 0.f) * wv.z + fmaxf(t3 + b2v.w, 0.f) * wv.w;
        // reduce over lanes 0..31 (sources stay within active guard)
        part += __shfl_down(part, 16, 64);
        part += __shfl_down(part, 8, 64);
        part += __shfl_down(part, 4, 64);
        part += __shfl_down(part, 2, 64);
        part += __shfl_down(part, 1, 64);
        if (lane == 0) out[v] = part + bfc[0];
    }
}

// ---------------- dense transforms (fp32, register-tiled) ----------------

// C = relu(A @ W + bias), A:[n,100], W:[100,256]. 64x64 tile, 4x4/thread.
__global__ __launch_bounds__(256) void gemm1_tiled(
        const float* __restrict__ A, const float* __restrict__ W,
        const float* __restrict__ bias, float* __restrict__ C, int n) {
    __shared__ float As[F0 * KPAD];
    __shared__ float Bs[F0 * KPAD];
    int tid = threadIdx.x;
    int r0 = blockIdx.x * 64;
    int c0 = blockIdx.y * 64;

    for (int idx = tid; idx < 64 * 25; idx += 256) {
        int row = idx / 25, kq = idx - row * 25;
        int gr = r0 + row;
        if (gr >= n) gr = n - 1;
        float4 v = ((const float4*)(A + (size_t)gr * F0))[kq];
        int k = 4 * kq;
        As[(k + 0) * KPAD + row] = v.x;
        As[(k + 1) * KPAD + row] = v.y;
        As[(k + 2) * KPAD + row] = v.z;
        As[(k + 3) * KPAD + row] = v.w;
    }
    for (int idx = tid; idx < F0 * 16; idx += 256) {
        int k = idx >> 4, cq = idx & 15;
        ((float4*)(Bs + k * KPAD))[cq] = ((const float4*)(W + k * F1 + c0))[cq];
    }
    __syncthreads();

    int tc = tid & 15, tr = tid >> 4;
    float acc[4][4] = {};
    for (int k = 0; k < F0; k++) {
        float4 a = *(const float4*)(As + k * KPAD + 4 * tr);
        float4 b = *(const float4*)(Bs + k * KPAD + 4 * tc);
        float av[4] = {a.x, a.y, a.z, a.w};
        float bv[4] = {b.x, b.y, b.z, b.w};
#pragma unroll
        for (int i = 0; i < 4; i++)
#pragma unroll
            for (int j = 0; j < 4; j++) acc[i][j] += av[i] * bv[j];
    }
    float4 bb = *(const float4*)(bias + c0 + 4 * tc);
    float bvv[4] = {bb.x, bb.y, bb.z, bb.w};
#pragma unroll
    for (int i = 0; i < 4; i++) {
        int gr = r0 + 4 * tr + i;
        if (gr < n) {
            float4 o;
            o.x = fmaxf(acc[i][0] + bvv[0], 0.f);
            o.y = fmaxf(acc[i][1] + bvv[1], 0.f);
            o.z = fmaxf(acc[i][2] + bvv[2], 0.f);
            o.w = fmaxf(acc[i][3] + bvv[3], 0.f);
            ((float4*)(C + (size_t)gr * F1 + c0))[tc] = o;
        }
    }
}

// C = A @ W, A:[n,256], W:[256,128]. 64x64 tile, 4x4/thread, K by 64.
__global__ __launch_bounds__(256) void gemm2_tiled(
        const float* __restrict__ A, const float* __restrict__ W,
        float* __restrict__ C, int n) {
    __shared__ float As[64 * KPAD];
    __shared__ float Bs[64 * KPAD];
    int tid = threadIdx.x;
    int r0 = blockIdx.x * 64;
    int c0 = blockIdx.y * 64;
    int tc = tid & 15, tr = tid >> 4;
    float acc[4][4] = {};

    for (int k0 = 0; k0 < F1; k0 += 64) {
        if (k0) __syncthreads();
        for (int idx = tid; idx < 64 * 16; idx += 256) {
            int row = idx >> 4, kq = idx & 15;
            int gr = r0 + row;
            if (gr >= n) gr = n - 1;
            float4 v = ((const float4*)(A + (size_t)gr * F1 + k0))[kq];
            int k = 4 * kq;
            As[(k + 0) * KPAD + row] = v.x;
            As[(k + 1) * KPAD + row] = v.y;
            As[(k + 2) * KPAD + row] = v.z;
            As[(k + 3) * KPAD + row] = v.w;
        }
        for (int idx = tid; idx < 64 * 16; idx += 256) {
            int k = idx >> 4, cq = idx & 15;
            ((float4*)(Bs + k * KPAD))[cq] =
                ((const float4*)(W + (k0 + k) * F2 + c0))[cq];
        }
        __syncthreads();
#pragma unroll 4
        for (int k = 0; k < 64; k++) {
            float4 a = *(const float4*)(As + k * KPAD + 4 * tr);
            float4 b = *(const float4*)(Bs + k * KPAD + 4 * tc);
            float av[4] = {a.x, a.y, a.z, a.w};
            float bv[4] = {b.x, b.y, b.z, b.w};
#pragma unroll
            for (int i = 0; i < 4; i++)
#pragma unroll
                for (int j = 0; j < 4; j++) acc[i][j] += av[i] * bv[j];
        }
    }
#pragma unroll
    for (int i = 0; i < 4; i++) {
        int gr = r0 + 4 * tr + i;
        if (gr < n) {
            float4 o = {acc[i][0], acc[i][1], acc[i][2], acc[i][3]};
            ((float4*)(C + (size_t)gr * F2 + c0))[tc] = o;
        }
    }
}

// ---------------- launch ----------------

static inline size_t align16(size_t x) { return (x + 3) & ~(size_t)3; }  // in 4B elems

extern "C" void kernel_launch(void* const* d_in, const int* in_sizes, int n_in,
                              void* d_out, int out_size, void* d_ws, size_t ws_size,
                              hipStream_t stream) {
    const float* x   = (const float*)d_in[0];
    const int*   ei  = (const int*)d_in[1];
    const float* W1  = (const float*)d_in[2];
    const float* b1  = (const float*)d_in[3];
    const float* W2  = (const float*)d_in[4];
    const float* b2  = (const float*)d_in[5];
    const float* Wfc = (const float*)d_in[6];
    const float* bfc = (const float*)d_in[7];
    float* out = (float*)d_out;

    const int n = in_sizes[0] / F0;   // 50000
    const int e = in_sizes[1] / 2;    // 800000
    const int* src = ei;
    const int* dst = ei + e;

    // workspace layout (4-byte elements, each region 16B-aligned)
    char* wsb = (char*)d_ws;
    size_t off = 0;
    int* deg    = (int*)(wsb + 4 * off); off = align16(off + n);
    int* rowptr = (int*)(wsb + 4 * off); off = align16(off + n + 1);
    int* cursor = (int*)(wsb + 4 * off); off = align16(off + n);
    int* csr    = (int*)(wsb + 4 * off); off = align16(off + e);
    float* dinv = (float*)(wsb + 4 * off); off = align16(off + n);
    float* aggX = (float*)(wsb + 4 * off); off = align16(off + (size_t)n * F0);
    float* a1   = (float*)(wsb + 4 * off); off = align16(off + (size_t)n * F1);
    float* h2   = (float*)(wsb + 4 * off); off = align16(off + (size_t)n * F2);

    const int B = 256;
    const int rblocks = (n + 63) / 64;

    // CSR build
    zero_i32<<<(n + B - 1) / B, B, 0, stream>>>(deg, n);
    deg_count_i<<<(e + B - 1) / B, B, 0, stream>>>(dst, deg, e);
    make_dinv<<<(n + B - 1) / B, B, 0, stream>>>(deg, dinv, n);
    scan_rowptr<<<1, 1024, 0, stream>>>(deg, rowptr, n);
    hipMemcpyAsync(cursor, rowptr, (size_t)n * 4, hipMemcpyDeviceToDevice, stream);
    csr_fill<<<(e + B - 1) / B, B, 0, stream>>>(src, dst, cursor, csr, e);

    // layer 1: pull-aggregate x (100-dim), then tiled GEMM + bias + relu
    pull_f100<<<(n + 3) / 4, 256, 0, stream>>>(x, rowptr, csr, dinv, aggX, n);
    gemm1_tiled<<<dim3(rblocks, F1 / 64), 256, 0, stream>>>(aggX, W1, b1, a1, n);

    // layer 2: tiled GEMM 256->128, then fused pull + bias + relu + FC
    gemm2_tiled<<<dim3(rblocks, F2 / 64), 256, 0, stream>>>(a1, W2, h2, n);
    pull_f128_fused<<<(n + 3) / 4, 256, 0, stream>>>(h2, rowptr, csr, dinv,
                                                     b2, Wfc, bfc, out, n);
}

// Round 6
// 389.968 us; speedup vs baseline: 2.5379x; 1.1407x over previous
//
#include <hip/hip_runtime.h>
#include <hip/hip_bf16.h>

// GCN: out = relu(gcnconv(relu(gcnconv(x,W1,b1)), W2, b2)) @ Wfc + bfc
// N=50000, E=800000, F0=100, F1=256, F2=128. All-fp32 value path (bf16 blows
// the ~6e-6 relative threshold — round-4 post-mortem).
// Round 6: GEMMs rebuilt as 128x128 tiles, 8x8 micro, k-major LDS with
// conflict-free row-fast transpose staging (round-5's kq-fast staging put 25
// lanes on 2 banks -> 6.4M conflict cycles). Hierarchical scan replaces the
// single-workgroup rowptr scan. Pull kernels unchanged from round 5.

#define F0 100
#define F1 256
#define F2 128

// ---------------- CSR construction ----------------

__global__ void zero_i32(int* p, int n) {
    int i = blockIdx.x * blockDim.x + threadIdx.x;
    if (i < n) p[i] = 0;
}

__global__ void deg_count_i(const int* __restrict__ dst, int* deg, int e) {
    int i = blockIdx.x * blockDim.x + threadIdx.x;
    if (i < e) atomicAdd(deg + dst[i], 1);
}

__global__ void make_dinv(const int* __restrict__ deg, float* __restrict__ dinv, int n) {
    int i = blockIdx.x * blockDim.x + threadIdx.x;
    if (i < n) dinv[i] = rsqrtf((float)(deg[i] + 1));
}

// hierarchical exclusive scan: scan1 (per-block excl + block sums),
// scan2 (scan block sums, write rowptr[n]=total), scan3 (add offsets).
__global__ __launch_bounds__(256) void scan1(const int* __restrict__ deg,
                                             int* __restrict__ excl,
                                             int* __restrict__ bsum, int n) {
    __shared__ int wsum[4];
    int i = blockIdx.x * 256 + threadIdx.x;
    int lane = threadIdx.x & 63, wid = threadIdx.x >> 6;
    int v = (i < n) ? deg[i] : 0;
    int s = v;
#pragma unroll
    for (int off = 1; off < 64; off <<= 1) {
        int t = __shfl_up(s, off, 64);
        if (lane >= off) s += t;
    }
    if (lane == 63) wsum[wid] = s;
    __syncthreads();
    int add = 0;
    for (int w = 0; w < wid; w++) add += wsum[w];
    if (i < n) excl[i] = add + s - v;
    if (threadIdx.x == 255) bsum[blockIdx.x] = add + s;
}

__global__ __launch_bounds__(256) void scan2(int* __restrict__ bsum, int nb,
                                             int* __restrict__ rowptr, int n) {
    __shared__ int wsum[4];
    int lane = threadIdx.x & 63, wid = threadIdx.x >> 6;
    int v = (threadIdx.x < nb) ? bsum[threadIdx.x] : 0;
    int s = v;
#pragma unroll
    for (int off = 1; off < 64; off <<= 1) {
        int t = __shfl_up(s, off, 64);
        if (lane >= off) s += t;
    }
    if (lane == 63) wsum[wid] = s;
    __syncthreads();
    int add = 0;
    for (int w = 0; w < wid; w++) add += wsum[w];
    if (threadIdx.x < nb) bsum[threadIdx.x] = add + s - v;
    if (threadIdx.x == 255) rowptr[n] = add + s;
}

__global__ void scan3(const int* __restrict__ excl, const int* __restrict__ bsum,
                      int* __restrict__ rowptr, int n) {
    int i = blockIdx.x * 256 + threadIdx.x;
    if (i < n) rowptr[i] = excl[i] + bsum[blockIdx.x];
}

__global__ void csr_fill(const int* __restrict__ src, const int* __restrict__ dst,
                         int* cursor, int* __restrict__ csr, int e) {
    int i = blockIdx.x * blockDim.x + threadIdx.x;
    if (i < e) {
        int pos = atomicAdd(cursor + dst[i], 1);
        csr[pos] = src[i];
    }
}

// ---------------- pull-gather aggregation (fp32, high-MLP) ----------------

// aggX[v][:] = dinv[v]*( sum_{s in in(v)} dinv[s]*x[s][:] + dinv[v]*x[v][:] )
// One wave/node. Row = 400B = 25 float4. Lanes 0-24 even edges, 32-56 odd.
__global__ __launch_bounds__(256) void pull_f100(
        const float* __restrict__ x, const int* __restrict__ rowptr,
        const int* __restrict__ csr, const float* __restrict__ dinv,
        float* __restrict__ agg, int n) {
    int wave = threadIdx.x >> 6, lane = threadIdx.x & 63;
    int v = blockIdx.x * 4 + wave;
    if (v >= n) return;
    int beg = rowptr[v], end = rowptr[v + 1];
    float dv = dinv[v];
    int half = lane >> 5;
    int q = lane & 31;
    bool act = q < 25;
    float4 acc = {0.f, 0.f, 0.f, 0.f};

    for (int base = beg; base < end; base += 64) {
        int cnt = min(64, end - base);
        int sidx = (lane < cnt) ? csr[base + lane] : v;
        float scoef = (lane < cnt) ? dinv[sidx] : 0.f;
        int npairs = (cnt + 1) >> 1;
        int p = 0;
        for (; p + 4 <= npairs; p += 4) {
            int s0 = __shfl(sidx, 2 * p + half, 64);
            int s1 = __shfl(sidx, 2 * (p + 1) + half, 64);
            int s2 = __shfl(sidx, 2 * (p + 2) + half, 64);
            int s3 = __shfl(sidx, 2 * (p + 3) + half, 64);
            float c0 = __shfl(scoef, 2 * p + half, 64);
            float c1 = __shfl(scoef, 2 * (p + 1) + half, 64);
            float c2 = __shfl(scoef, 2 * (p + 2) + half, 64);
            float c3 = __shfl(scoef, 2 * (p + 3) + half, 64);
            if (act) {
                float4 r0 = ((const float4*)(x + (size_t)s0 * F0))[q];
                float4 r1 = ((const float4*)(x + (size_t)s1 * F0))[q];
                float4 r2 = ((const float4*)(x + (size_t)s2 * F0))[q];
                float4 r3 = ((const float4*)(x + (size_t)s3 * F0))[q];
                acc.x += c0 * r0.x + c1 * r1.x + c2 * r2.x + c3 * r3.x;
                acc.y += c0 * r0.y + c1 * r1.y + c2 * r2.y + c3 * r3.y;
                acc.z += c0 * r0.z + c1 * r1.z + c2 * r2.z + c3 * r3.z;
                acc.w += c0 * r0.w + c1 * r1.w + c2 * r2.w + c3 * r3.w;
            }
        }
        for (; p < npairs; p++) {
            int s0 = __shfl(sidx, 2 * p + half, 64);
            float c0 = __shfl(scoef, 2 * p + half, 64);
            if (act) {
                float4 r0 = ((const float4*)(x + (size_t)s0 * F0))[q];
                acc.x += c0 * r0.x;
                acc.y += c0 * r0.y;
                acc.z += c0 * r0.z;
                acc.w += c0 * r0.w;
            }
        }
    }
    float ox = __shfl_down(acc.x, 32, 64);
    float oy = __shfl_down(acc.y, 32, 64);
    float oz = __shfl_down(acc.z, 32, 64);
    float ow = __shfl_down(acc.w, 32, 64);
    if (half == 0 && act) {
        float4 hv = ((const float4*)(x + (size_t)v * F0))[q];
        float4 r;
        r.x = dv * (acc.x + ox + dv * hv.x);
        r.y = dv * (acc.y + oy + dv * hv.y);
        r.z = dv * (acc.z + oz + dv * hv.z);
        r.w = dv * (acc.w + ow + dv * hv.w);
        ((float4*)(agg + (size_t)v * F0))[q] = r;
    }
}

// Fused layer-2 aggregation + bias + relu + final FC. Row = 512B = 32 float4.
__global__ __launch_bounds__(256) void pull_f128_fused(
        const float* __restrict__ h2, const int* __restrict__ rowptr,
        const int* __restrict__ csr, const float* __restrict__ dinv,
        const float* __restrict__ b2, const float* __restrict__ Wfc,
        const float* __restrict__ bfc, float* __restrict__ out, int n) {
    int wave = threadIdx.x >> 6, lane = threadIdx.x & 63;
    int v = blockIdx.x * 4 + wave;
    if (v >= n) return;
    int beg = rowptr[v], end = rowptr[v + 1];
    float dv = dinv[v];
    int half = lane >> 5;
    int q = lane & 31;
    float4 acc = {0.f, 0.f, 0.f, 0.f};

    for (int base = beg; base < end; base += 64) {
        int cnt = min(64, end - base);
        int sidx = (lane < cnt) ? csr[base + lane] : v;
        float scoef = (lane < cnt) ? dinv[sidx] : 0.f;
        int npairs = (cnt + 1) >> 1;
        int p = 0;
        for (; p + 4 <= npairs; p += 4) {
            int s0 = __shfl(sidx, 2 * p + half, 64);
            int s1 = __shfl(sidx, 2 * (p + 1) + half, 64);
            int s2 = __shfl(sidx, 2 * (p + 2) + half, 64);
            int s3 = __shfl(sidx, 2 * (p + 3) + half, 64);
            float c0 = __shfl(scoef, 2 * p + half, 64);
            float c1 = __shfl(scoef, 2 * (p + 1) + half, 64);
            float c2 = __shfl(scoef, 2 * (p + 2) + half, 64);
            float c3 = __shfl(scoef, 2 * (p + 3) + half, 64);
            float4 r0 = ((const float4*)(h2 + (size_t)s0 * F2))[q];
            float4 r1 = ((const float4*)(h2 + (size_t)s1 * F2))[q];
            float4 r2 = ((const float4*)(h2 + (size_t)s2 * F2))[q];
            float4 r3 = ((const float4*)(h2 + (size_t)s3 * F2))[q];
            acc.x += c0 * r0.x + c1 * r1.x + c2 * r2.x + c3 * r3.x;
            acc.y += c0 * r0.y + c1 * r1.y + c2 * r2.y + c3 * r3.y;
            acc.z += c0 * r0.z + c1 * r1.z + c2 * r2.z + c3 * r3.z;
            acc.w += c0 * r0.w + c1 * r1.w + c2 * r2.w + c3 * r3.w;
        }
        for (; p < npairs; p++) {
            int s0 = __shfl(sidx, 2 * p + half, 64);
            float c0 = __shfl(scoef, 2 * p + half, 64);
            float4 r0 = ((const float4*)(h2 + (size_t)s0 * F2))[q];
            acc.x += c0 * r0.x;
            acc.y += c0 * r0.y;
            acc.z += c0 * r0.z;
            acc.w += c0 * r0.w;
        }
    }
    float ox = __shfl_down(acc.x, 32, 64);
    float oy = __shfl_down(acc.y, 32, 64);
    float oz = __shfl_down(acc.z, 32, 64);
    float ow = __shfl_down(acc.w, 32, 64);
    float part = 0.f;
    if (half == 0) {
        float4 hv = ((const float4*)(h2 + (size_t)v * F2))[q];
        float4 b2v = ((const float4*)b2)[q];
        float4 wv = ((const float4*)Wfc)[q];
        float t0 = dv * (acc.x + ox + dv * hv.x);
        float t1 = dv * (acc.y + oy + dv * hv.y);
        float t2 = dv * (acc.z + oz + dv * hv.z);
        float t3 = dv * (acc.w + ow + dv * hv.w);
        part = fmaxf(t0 + b2v.x, 0.f) * wv.x + fmaxf(t1 + b2v.y, 0.f) * wv.y +
               fmaxf(t2 + b2v.z, 0.f) * wv.z + fmaxf(t3 + b2v.w, 0.f) * wv.w;
        part += __shfl_down(part, 16, 64);
        part += __shfl_down(part, 8, 64);
        part += __shfl_down(part, 4, 64);
        part += __shfl_down(part, 2, 64);
        part += __shfl_down(part, 1, 64);
        if (lane == 0) out[v] = part + bfc[0];
    }
}

// ---------------- dense transforms (fp32, 128x128 tile, 8x8 micro) --------

// C = relu(A @ W + bias), A:[n,100], W:[100,256]. K chunked by 20.
// k-major LDS stride 128; thread row clusters {4tr,64+4tr}, col {4tc,64+4tc}.
__global__ __launch_bounds__(256) void gemm1_tiled(
        const float* __restrict__ A, const float* __restrict__ W,
        const float* __restrict__ bias, float* __restrict__ C, int n) {
    __shared__ float As[20 * 128];
    __shared__ float Bs[20 * 128];
    int tid = threadIdx.x;
    int r0 = blockIdx.x * 128;
    int c0 = blockIdx.y * 128;
    int tc = tid & 15, tr = tid >> 4;
    float acc[8][8] = {};

    for (int k0 = 0; k0 < F0; k0 += 20) {
        if (k0) __syncthreads();
        // stage A: transpose to k-major, lanes row-fast (bank-conflict-free)
        for (int idx = tid; idx < 128 * 5; idx += 256) {
            int row = idx & 127, kq = idx >> 7;  // kq 0..4
            int gr = r0 + row;
            if (gr >= n) gr = n - 1;
            float4 v = *(const float4*)(A + (size_t)gr * F0 + k0 + 4 * kq);
            As[(4 * kq + 0) * 128 + row] = v.x;
            As[(4 * kq + 1) * 128 + row] = v.y;
            As[(4 * kq + 2) * 128 + row] = v.z;
            As[(4 * kq + 3) * 128 + row] = v.w;
        }
        // stage B: direct copy, 20 k x 32 float4
        for (int idx = tid; idx < 20 * 32; idx += 256) {
            int k = idx >> 5, cq = idx & 31;
            *(float4*)(Bs + k * 128 + 4 * cq) =
                *(const float4*)(W + (size_t)(k0 + k) * F1 + c0 + 4 * cq);
        }
        __syncthreads();
#pragma unroll 5
        for (int k = 0; k < 20; k++) {
            float4 a0 = *(const float4*)(As + k * 128 + 4 * tr);
            float4 a1 = *(const float4*)(As + k * 128 + 64 + 4 * tr);
            float4 b0 = *(const float4*)(Bs + k * 128 + 4 * tc);
            float4 b1 = *(const float4*)(Bs + k * 128 + 64 + 4 * tc);
            float av[8] = {a0.x, a0.y, a0.z, a0.w, a1.x, a1.y, a1.z, a1.w};
            float bv[8] = {b0.x, b0.y, b0.z, b0.w, b1.x, b1.y, b1.z, b1.w};
#pragma unroll
            for (int i = 0; i < 8; i++)
#pragma unroll
                for (int j = 0; j < 8; j++) acc[i][j] += av[i] * bv[j];
        }
    }
    float4 bb0 = *(const float4*)(bias + c0 + 4 * tc);
    float4 bb1 = *(const float4*)(bias + c0 + 64 + 4 * tc);
    float bv[8] = {bb0.x, bb0.y, bb0.z, bb0.w, bb1.x, bb1.y, bb1.z, bb1.w};
#pragma unroll
    for (int i = 0; i < 8; i++) {
        int row = (i < 4) ? (4 * tr + i) : (64 + 4 * tr + i - 4);
        int gr = r0 + row;
        if (gr < n) {
            float4 o0, o1;
            o0.x = fmaxf(acc[i][0] + bv[0], 0.f);
            o0.y = fmaxf(acc[i][1] + bv[1], 0.f);
            o0.z = fmaxf(acc[i][2] + bv[2], 0.f);
            o0.w = fmaxf(acc[i][3] + bv[3], 0.f);
            o1.x = fmaxf(acc[i][4] + bv[4], 0.f);
            o1.y = fmaxf(acc[i][5] + bv[5], 0.f);
            o1.z = fmaxf(acc[i][6] + bv[6], 0.f);
            o1.w = fmaxf(acc[i][7] + bv[7], 0.f);
            *(float4*)(C + (size_t)gr * F1 + c0 + 4 * tc) = o0;
            *(float4*)(C + (size_t)gr * F1 + c0 + 64 + 4 * tc) = o1;
        }
    }
}

// C = A @ W, A:[n,256], W:[256,128]. Tile 128 rows x 128 cols (full F2),
// K chunked by 32.
__global__ __launch_bounds__(256) void gemm2_tiled(
        const float* __restrict__ A, const float* __restrict__ W,
        float* __restrict__ C, int n) {
    __shared__ float As[32 * 128];
    __shared__ float Bs[32 * 128];
    int tid = threadIdx.x;
    int r0 = blockIdx.x * 128;
    int tc = tid & 15, tr = tid >> 4;
    float acc[8][8] = {};

    for (int k0 = 0; k0 < F1; k0 += 32) {
        if (k0) __syncthreads();
        for (int idx = tid; idx < 128 * 8; idx += 256) {
            int row = idx & 127, kq = idx >> 7;  // kq 0..7
            int gr = r0 + row;
            if (gr >= n) gr = n - 1;
            float4 v = *(const float4*)(A + (size_t)gr * F1 + k0 + 4 * kq);
            As[(4 * kq + 0) * 128 + row] = v.x;
            As[(4 * kq + 1) * 128 + row] = v.y;
            As[(4 * kq + 2) * 128 + row] = v.z;
            As[(4 * kq + 3) * 128 + row] = v.w;
        }
        for (int idx = tid; idx < 32 * 32; idx += 256) {
            int k = idx >> 5, cq = idx & 31;
            *(float4*)(Bs + k * 128 + 4 * cq) =
                *(const float4*)(W + (size_t)(k0 + k) * F2 + 4 * cq);
        }
        __syncthreads();
#pragma unroll 4
        for (int k = 0; k < 32; k++) {
            float4 a0 = *(const float4*)(As + k * 128 + 4 * tr);
            float4 a1 = *(const float4*)(As + k * 128 + 64 + 4 * tr);
            float4 b0 = *(const float4*)(Bs + k * 128 + 4 * tc);
            float4 b1 = *(const float4*)(Bs + k * 128 + 64 + 4 * tc);
            float av[8] = {a0.x, a0.y, a0.z, a0.w, a1.x, a1.y, a1.z, a1.w};
            float bv[8] = {b0.x, b0.y, b0.z, b0.w, b1.x, b1.y, b1.z, b1.w};
#pragma unroll
            for (int i = 0; i < 8; i++)
#pragma unroll
                for (int j = 0; j < 8; j++) acc[i][j] += av[i] * bv[j];
        }
    }
#pragma unroll
    for (int i = 0; i < 8; i++) {
        int row = (i < 4) ? (4 * tr + i) : (64 + 4 * tr + i - 4);
        int gr = r0 + row;
        if (gr < n) {
            float4 o0 = {acc[i][0], acc[i][1], acc[i][2], acc[i][3]};
            float4 o1 = {acc[i][4], acc[i][5], acc[i][6], acc[i][7]};
            *(float4*)(C + (size_t)gr * F2 + 4 * tc) = o0;
            *(float4*)(C + (size_t)gr * F2 + 64 + 4 * tc) = o1;
        }
    }
}

// ---------------- launch ----------------

static inline size_t align16(size_t x) { return (x + 3) & ~(size_t)3; }  // in 4B elems

extern "C" void kernel_launch(void* const* d_in, const int* in_sizes, int n_in,
                              void* d_out, int out_size, void* d_ws, size_t ws_size,
                              hipStream_t stream) {
    const float* x   = (const float*)d_in[0];
    const int*   ei  = (const int*)d_in[1];
    const float* W1  = (const float*)d_in[2];
    const float* b1  = (const float*)d_in[3];
    const float* W2  = (const float*)d_in[4];
    const float* b2  = (const float*)d_in[5];
    const float* Wfc = (const float*)d_in[6];
    const float* bfc = (const float*)d_in[7];
    float* out = (float*)d_out;

    const int n = in_sizes[0] / F0;   // 50000
    const int e = in_sizes[1] / 2;    // 800000
    const int* src = ei;
    const int* dst = ei + e;

    // workspace layout (4-byte elements, each region 16B-aligned)
    char* wsb = (char*)d_ws;
    size_t off = 0;
    int* deg    = (int*)(wsb + 4 * off); off = align16(off + n);
    int* excl   = (int*)(wsb + 4 * off); off = align16(off + n);
    int* bsum   = (int*)(wsb + 4 * off); off = align16(off + 256);
    int* rowptr = (int*)(wsb + 4 * off); off = align16(off + n + 1);
    int* cursor = (int*)(wsb + 4 * off); off = align16(off + n);
    int* csr    = (int*)(wsb + 4 * off); off = align16(off + e);
    float* dinv = (float*)(wsb + 4 * off); off = align16(off + n);
    float* aggX = (float*)(wsb + 4 * off); off = align16(off + (size_t)n * F0);
    float* a1   = (float*)(wsb + 4 * off); off = align16(off + (size_t)n * F1);
    float* h2   = (float*)(wsb + 4 * off); off = align16(off + (size_t)n * F2);

    const int B = 256;
    const int nb = (n + B - 1) / B;          // 196 (must be <= 256)
    const int rblocks = (n + 127) / 128;     // 391

    // CSR build
    zero_i32<<<nb, B, 0, stream>>>(deg, n);
    deg_count_i<<<(e + B - 1) / B, B, 0, stream>>>(dst, deg, e);
    make_dinv<<<nb, B, 0, stream>>>(deg, dinv, n);
    scan1<<<nb, B, 0, stream>>>(deg, excl, bsum, n);
    scan2<<<1, B, 0, stream>>>(bsum, nb, rowptr, n);
    scan3<<<nb, B, 0, stream>>>(excl, bsum, rowptr, n);
    hipMemcpyAsync(cursor, rowptr, (size_t)n * 4, hipMemcpyDeviceToDevice, stream);
    csr_fill<<<(e + B - 1) / B, B, 0, stream>>>(src, dst, cursor, csr, e);

    // layer 1: pull-aggregate x (100-dim), then tiled GEMM + bias + relu
    pull_f100<<<(n + 3) / 4, 256, 0, stream>>>(x, rowptr, csr, dinv, aggX, n);
    gemm1_tiled<<<dim3(rblocks, F1 / 128), 256, 0, stream>>>(aggX, W1, b1, a1, n);

    // layer 2: tiled GEMM 256->128, then fused pull + bias + relu + FC
    gemm2_tiled<<<rblocks, 256, 0, stream>>>(a1, W2, h2, n);
    pull_f128_fused<<<(n + 3) / 4, 256, 0, stream>>>(h2, rowptr, csr, dinv,
                                                     b2, Wfc, bfc, out, n);
}